// Round 1
// baseline (274.734 us; speedup 1.0000x reference)
//
#include <hip/hip_runtime.h>

// Round-6: wave-autonomous single-pass cumulative max along H.
// Round-5 post-mortem: per-chunk __syncthreads forces s_waitcnt vmcnt(0)
// before s_barrier -> the register prefetch and the previous chunk's stores
// fully drain every chunk. Memory pipe runs in synchronized bursts (HBM 29%,
// VALU 8.6%, occupancy 27.5% => latency-bound, not BW-bound).
// Fix: NO barriers, NO LDS. Each wave owns a 64 B-wide column strip
// (4 float4) for the whole H=1024 of one batch image:
//   lane = hseg*4 + w   (w: float4-col 0..3, hseg: h-segment 0..15)
//   chunk = 128 rows (R=8 rows/lane), NCHUNK = 8
// Per chunk: 8 prefetch loads (next chunk), R-row register max, 16-segment
// inclusive scan via 4 __shfl_up rounds (stride 4), carry folded from a
// register (no cross-wave exchange), 8 stores. Waves free-run; the only
// waits are counted vmcnt for the wave's own prefetch, so loads/stores from
// adjacent chunks stay in flight continuously.
// Grid: 32 b x 64 strips = 2048 waves, 4 waves/block (512 blocks). The 4
// waves of a block cover 4 ADJACENT 64 B strips = a contiguous 256 B span,
// so every 128 B L2 line is read/dirtied by one CU only (no cross-XCD line
// split, full-line writebacks despite 64 B-granular instructions).

constexpr int B = 32;
constexpr int H = 1024;
constexpr int W = 1024;
constexpr int ROW4 = W / 4;          // 256 float4 per row
constexpr int SW4 = 4;               // strip width per wave: 4 float4 = 64 B
constexpr int NSTRIP = ROW4 / SW4;   // 64 strips per b
constexpr int NSEG = 64 / SW4;       // 16 h-segments per wave
constexpr int R = 8;                 // rows per lane per chunk
constexpr int CH = NSEG * R;         // 128 rows per chunk
constexpr int NCHUNK = H / CH;       // 8
constexpr int WPB = 4;               // waves per block
constexpr int NBLK = B * NSTRIP / WPB;  // 512 blocks

__device__ __forceinline__ float4 max4(float4 a, float4 b) {
    return make_float4(fmaxf(a.x, b.x), fmaxf(a.y, b.y),
                       fmaxf(a.z, b.z), fmaxf(a.w, b.w));
}

__device__ __forceinline__ float4 shflup4(float4 v, int d) {
    float4 r;
    r.x = __shfl_up(v.x, d, 64);
    r.y = __shfl_up(v.y, d, 64);
    r.z = __shfl_up(v.z, d, 64);
    r.w = __shfl_up(v.w, d, 64);
    return r;
}

__device__ __forceinline__ float4 shfl4(float4 v, int src) {
    float4 r;
    r.x = __shfl(v.x, src, 64);
    r.y = __shfl(v.y, src, 64);
    r.z = __shfl(v.z, src, 64);
    r.w = __shfl(v.w, src, 64);
    return r;
}

__global__ __launch_bounds__(256) void cummax_wave(const float* __restrict__ xf,
                                                   float* __restrict__ of) {
    const int lane = threadIdx.x & 63;
    const int wid = threadIdx.x >> 6;
    const int gid = blockIdx.x * WPB + wid;   // 0..2047: one wave per strip
    const int b = gid >> 6;                   // gid / NSTRIP
    const int strip = gid & (NSTRIP - 1);
    const int w = lane & (SW4 - 1);           // float4-col within strip
    const int hseg = lane >> 2;               // 0..15

    const float4* x4 = (const float4*)xf;
    float4* o4 = (float4*)of;
    const size_t tbase = (size_t)b * (H * ROW4) + (size_t)strip * SW4 + w;

    const float ninf = -__builtin_inff();
    const float4 ninf4 = make_float4(ninf, ninf, ninf, ninf);
    float4 carry = ninf4;

    float4 cur[R], nxt[R];

#pragma unroll
    for (int r = 0; r < R; ++r)
        cur[r] = x4[tbase + (size_t)(hseg * R + r) * ROW4];

#pragma unroll
    for (int c = 0; c < NCHUNK; ++c) {
        // prefetch chunk c+1; stays in flight across this chunk's compute
        // and stores (no barrier anywhere to drain it)
        if (c + 1 < NCHUNK) {
#pragma unroll
            for (int r = 0; r < R; ++r)
                nxt[r] = x4[tbase + (size_t)((c + 1) * CH + hseg * R + r) * ROW4];
        }

        // this lane's segment max over its R rows
        float4 m = cur[0];
#pragma unroll
        for (int r = 1; r < R; ++r) m = max4(m, cur[r]);

        // inclusive shuffle scan over the 16 h-segments (stride 4 lanes)
        float4 incl = m;
        { float4 t = shflup4(incl, 4);  if (lane >= 4)  incl = max4(incl, t); }
        { float4 t = shflup4(incl, 8);  if (lane >= 8)  incl = max4(incl, t); }
        { float4 t = shflup4(incl, 16); if (lane >= 16) incl = max4(incl, t); }
        { float4 t = shflup4(incl, 32); if (lane >= 32) incl = max4(incl, t); }

        // exclusive prefix for this segment + carry from previous chunks
        float4 ew = shflup4(incl, 4);
        float4 pre = carry;
        if (hseg != 0) pre = max4(pre, ew);

        // chunk total = incl at hseg==15 (lanes 60..63), one per column
        float4 tot = shfl4(incl, 60 + w);
        carry = max4(carry, tot);

        // apply running max + store
        float4 a = pre;
#pragma unroll
        for (int r = 0; r < R; ++r) {
            a = max4(a, cur[r]);
            o4[tbase + (size_t)(c * CH + hseg * R + r) * ROW4] = a;
        }

        if (c + 1 < NCHUNK) {
#pragma unroll
            for (int r = 0; r < R; ++r) cur[r] = nxt[r];
        }
    }
}

extern "C" void kernel_launch(void* const* d_in, const int* in_sizes, int n_in,
                              void* d_out, int out_size, void* d_ws, size_t ws_size,
                              hipStream_t stream) {
    const float* x = (const float*)d_in[0];
    float* out = (float*)d_out;
    cummax_wave<<<NBLK, 256, 0, stream>>>(x, out);
}

// Round 2
// 259.272 us; speedup vs baseline: 1.0596x; 1.0596x over previous
//
#include <hip/hip_runtime.h>

// Round-7: two-kernel segment scan with ROW-CONTIGUOUS access.
// Round-6 post-mortem: barrier-free wave-autonomous kernel achieved the SAME
// 2.33 TB/s as the barrier-locked round-5 kernel (plus 12% write + 27% fetch
// inflation from 64 B strips). BW cap is wave-count-independent => not
// latency, not barriers. Shared trait of both losers: every memory
// instruction touches 8-16 lines at exactly 4 KB stride (column-walking) =>
// channel/bank serialization caps the pattern at ~2.3 TB/s.
// Fix: every instruction covers one contiguous 4 KB row (256 thr x float4).
//   A: block (b,s) -> column-max of its 32-row segment -> totals[b][s][:]
//      (4 MiB in d_ws). B: carry = predicated max over totals[b][k<s]
//      (L2-resident), then stream 32 rows load->max->store. No LDS, no
//      shuffles, no barriers; H-dependency lives in the tiny totals tensor.
// Input is L3-resident across iters (round-5 FETCH = 64 MB = half input), so
// reading x twice costs ~one extra L3 pass, while the write stream becomes
// full-line and channel-parallel.

constexpr int B = 32;
constexpr int H = 1024;
constexpr int W = 1024;
constexpr int ROW4 = W / 4;        // 256 float4 per row = 4 KB
constexpr int NSEG = 32;           // segments along H
constexpr int SH = H / NSEG;       // 32 rows per segment
constexpr int NB = B * NSEG;       // 1024 blocks
constexpr size_t TOT_BYTES = (size_t)NB * ROW4 * sizeof(float4);  // 4 MiB

__device__ __forceinline__ float4 max4(float4 a, float4 b) {
    return make_float4(fmaxf(a.x, b.x), fmaxf(a.y, b.y),
                       fmaxf(a.z, b.z), fmaxf(a.w, b.w));
}

// ---------------- kernel A: per-(b,seg) column max ----------------
__global__ __launch_bounds__(256) void seg_colmax(const float* __restrict__ xf,
                                                  float* __restrict__ tf) {
    const int id = blockIdx.x;
    const int b = id >> 5;
    const int s = id & (NSEG - 1);
    const int t = threadIdx.x;
    const float4* x4 = (const float4*)xf;
    float4* t4 = (float4*)tf;

    const size_t base = ((size_t)b * H + (size_t)s * SH) * ROW4 + t;
    const float ninf = -__builtin_inff();
    float4 m = make_float4(ninf, ninf, ninf, ninf);

#pragma unroll
    for (int g = 0; g < SH; g += 8) {
        float4 v[8];
#pragma unroll
        for (int r = 0; r < 8; ++r) v[r] = x4[base + (size_t)(g + r) * ROW4];
#pragma unroll
        for (int r = 0; r < 8; ++r) m = max4(m, v[r]);
    }
    t4[(size_t)id * ROW4 + t] = m;
}

// ------------- kernel B: carry from totals + stream segment -------------
__global__ __launch_bounds__(256) void seg_apply(const float* __restrict__ xf,
                                                 const float* __restrict__ tf,
                                                 float* __restrict__ of) {
    // XCD-chunk swizzle (bijective: 1024 = 8*128): same-image blocks land on
    // the same XCD so the shared totals[b][*] rows stay L2-local.
    const int id0 = blockIdx.x;
    const int id = (id0 & 7) * (NB / 8) + (id0 >> 3);
    const int b = id >> 5;
    const int s = id & (NSEG - 1);
    const int t = threadIdx.x;
    const float4* x4 = (const float4*)xf;
    const float4* t4 = (const float4*)tf;
    float4* o4 = (float4*)of;

    const float ninf = -__builtin_inff();
    float4 carry = make_float4(ninf, ninf, ninf, ninf);

    // predicated, fully-unrolled lookback over segment totals k < s
    // (branch is wave-uniform; loads are L2/L3-resident 4 KB rows)
#pragma unroll
    for (int g = 0; g < NSEG; g += 8) {
        float4 v[8];
#pragma unroll
        for (int k = 0; k < 8; ++k)
            v[k] = t4[(size_t)(b * NSEG + g + k) * ROW4 + t];
#pragma unroll
        for (int k = 0; k < 8; ++k)
            if (g + k < s) carry = max4(carry, v[k]);
    }

    const size_t base = ((size_t)b * H + (size_t)s * SH) * ROW4 + t;
    float4 m = carry;
#pragma unroll
    for (int g = 0; g < SH; g += 8) {
        float4 v[8];
#pragma unroll
        for (int r = 0; r < 8; ++r) v[r] = x4[base + (size_t)(g + r) * ROW4];
#pragma unroll
        for (int r = 0; r < 8; ++r) {
            m = max4(m, v[r]);
            o4[base + (size_t)(g + r) * ROW4] = m;
        }
    }
}

// ---------------- fallback (round-5 kernel) if ws too small ----------------
constexpr int F_SW4 = 8;
constexpr int F_NSTRIP = ROW4 / F_SW4;
constexpr int F_CH = 128;
constexpr int F_NCHUNK = H / F_CH;
constexpr int F_R = 4;

__device__ __forceinline__ float4 shflup4(float4 v, int d) {
    float4 r;
    r.x = __shfl_up(v.x, d, 64);
    r.y = __shfl_up(v.y, d, 64);
    r.z = __shfl_up(v.z, d, 64);
    r.w = __shfl_up(v.w, d, 64);
    return r;
}

__global__ __launch_bounds__(256) void cummax_sp(const float* __restrict__ xf,
                                                 float* __restrict__ of) {
    __shared__ float4 wavetot[2][32];
    const int tid = threadIdx.x;
    const int lane = tid & 63;
    const int wid = tid >> 6;
    const int w = tid & 7;
    const int hsegG = tid >> 3;
    const int hseg_l = (tid >> 3) & 7;
    const int b = blockIdx.x >> 5;
    const int strip = blockIdx.x & (F_NSTRIP - 1);
    const float4* x4 = (const float4*)xf;
    float4* o4 = (float4*)of;
    const size_t tbase = (size_t)b * (H * ROW4) + (size_t)strip * F_SW4 + w;
    const float ninf = -__builtin_inff();
    const float4 ninf4 = make_float4(ninf, ninf, ninf, ninf);
    float4 carry = ninf4;
    float4 cur[F_R], nxt[F_R];
#pragma unroll
    for (int r = 0; r < F_R; ++r)
        cur[r] = x4[tbase + (size_t)(hsegG * F_R + r) * ROW4];
#pragma unroll
    for (int c = 0; c < F_NCHUNK; ++c) {
        if (c + 1 < F_NCHUNK) {
#pragma unroll
            for (int r = 0; r < F_R; ++r)
                nxt[r] = x4[tbase + (size_t)((c + 1) * F_CH + hsegG * F_R + r) * ROW4];
        }
        float4 m = max4(max4(cur[0], cur[1]), max4(cur[2], cur[3]));
        float4 incl = m;
        { float4 t = shflup4(incl, 8);  if (lane >= 8)  incl = max4(incl, t); }
        { float4 t = shflup4(incl, 16); if (lane >= 16) incl = max4(incl, t); }
        { float4 t = shflup4(incl, 32); if (lane >= 32) incl = max4(incl, t); }
        float4 ew = shflup4(incl, 8);
        float4 excl = (hseg_l == 0) ? ninf4 : ew;
        if (hseg_l == 7) wavetot[c & 1][wid * 8 + w] = incl;
        __syncthreads();
        float4 crosspre = carry;
        float4 tot = carry;
#pragma unroll
        for (int w2 = 0; w2 < 4; ++w2) {
            float4 v = wavetot[c & 1][w2 * 8 + w];
            if (w2 < wid) crosspre = max4(crosspre, v);
            tot = max4(tot, v);
        }
        carry = tot;
        float4 a = max4(crosspre, excl);
#pragma unroll
        for (int r = 0; r < F_R; ++r) {
            a = max4(a, cur[r]);
            o4[tbase + (size_t)(c * F_CH + hsegG * F_R + r) * ROW4] = a;
        }
        if (c + 1 < F_NCHUNK) {
#pragma unroll
            for (int r = 0; r < F_R; ++r) cur[r] = nxt[r];
        }
    }
}

extern "C" void kernel_launch(void* const* d_in, const int* in_sizes, int n_in,
                              void* d_out, int out_size, void* d_ws, size_t ws_size,
                              hipStream_t stream) {
    const float* x = (const float*)d_in[0];
    float* out = (float*)d_out;
    if (ws_size >= TOT_BYTES && d_ws != nullptr) {
        float* tot = (float*)d_ws;
        seg_colmax<<<NB, 256, 0, stream>>>(x, tot);
        seg_apply<<<NB, 256, 0, stream>>>(x, tot, out);
    } else {
        cummax_sp<<<B * F_NSTRIP, 256, 0, stream>>>(x, out);
    }
}